// Round 8
// baseline (594.856 us; speedup 1.0000x reference)
//
#include <hip/hip_runtime.h>
#include <stdint.h>

#define NN 100000
#define NE 1600000
#define ET (NE + NN)
#define HC 128
#define HID 64
#define NCLS 12
#define BSZ 512
#define NBK ((NN + BSZ - 1) / BSZ)      // 196
#define CHUNK 8192
#define NPB ((ET + CHUNK - 1) / CHUNK)  // 208

typedef _Float16 f16;
typedef _Float16 f16x2 __attribute__((ext_vector_type(2)));
typedef _Float16 f16x4 __attribute__((ext_vector_type(4)));
typedef _Float16 f16x8 __attribute__((ext_vector_type(8)));
typedef float f32x4 __attribute__((ext_vector_type(4)));

// ---------- CSR build: bucketed counting sort, no global atomics ----------
__global__ __launch_bounds__(256) void k_hist(const int* __restrict__ ei, int* __restrict__ hgrid) {
    __shared__ int h[NBK];
    int tid = threadIdx.x;
    for (int b = tid; b < NBK; b += 256) h[b] = 0;
    __syncthreads();
    long base = (long)blockIdx.x * CHUNK;
#pragma unroll
    for (int k = 0; k < CHUNK / 256; k++) {
        long i = base + k * 256 + tid;
        if (i < ET) {
            int d = (i < NE) ? ei[NE + i] : (int)(i - NE);
            atomicAdd(&h[d >> 9], 1);
        }
    }
    __syncthreads();
    for (int b = tid; b < NBK; b += 256) hgrid[blockIdx.x * NBK + b] = h[b];
}

__global__ __launch_bounds__(256) void k_bscan(int* __restrict__ hgrid,
                                               int* __restrict__ bucketStart,
                                               int* __restrict__ rp) {
    __shared__ int s[256];
    int tid = threadIdx.x;
    int tot = 0;
    if (tid < NBK)
        for (int b = 0; b < NPB; b++) tot += hgrid[b * NBK + tid];
    s[tid] = tot;
    __syncthreads();
    for (int o = 1; o < 256; o <<= 1) {
        int t = (tid >= o) ? s[tid - o] : 0;
        __syncthreads();
        s[tid] += t;
        __syncthreads();
    }
    int excl = s[tid] - tot;
    if (tid < NBK) {
        bucketStart[tid] = excl;
        int run = excl;
        for (int b = 0; b < NPB; b++) {
            int t = hgrid[b * NBK + tid];
            hgrid[b * NBK + tid] = run;
            run += t;
        }
    }
    if (tid == 0) { bucketStart[NBK] = ET; rp[NN] = ET; }
}

__global__ __launch_bounds__(256) void k_part(const int* __restrict__ ei,
                                              const int* __restrict__ hgrid,
                                              uint32_t* __restrict__ ebuf) {
    __shared__ int h[NBK];
    __shared__ int base[NBK];
    int tid = threadIdx.x;
    for (int b = tid; b < NBK; b += 256) {
        base[b] = hgrid[blockIdx.x * NBK + b];
        h[b] = 0;
    }
    __syncthreads();
    long cbase = (long)blockIdx.x * CHUNK;
#pragma unroll
    for (int k = 0; k < CHUNK / 256; k++) {
        long i = cbase + k * 256 + tid;
        if (i < ET) {
            int s, d;
            if (i < NE) { s = ei[i]; d = ei[NE + i]; } else { s = d = (int)(i - NE); }
            int bk = d >> 9;
            int off = atomicAdd(&h[bk], 1);
            ebuf[base[bk] + off] = (uint32_t)s | ((uint32_t)(d & 511) << 17);
        }
    }
}

__global__ __launch_bounds__(512) void k_build(const uint32_t* __restrict__ ebuf,
                                               const int* __restrict__ bucketStart,
                                               int* __restrict__ rp, int* __restrict__ colx) {
    __shared__ int cnt[BSZ];
    __shared__ int fill[BSZ];
    int b = blockIdx.x, tid = threadIdx.x;
    int e0 = bucketStart[b], e1 = bucketStart[b + 1], m = e1 - e0;
    cnt[tid] = 0;
    __syncthreads();
    for (int k = tid; k < m; k += 512) atomicAdd(&cnt[ebuf[e0 + k] >> 17], 1);
    __syncthreads();
    int v = cnt[tid];
    __syncthreads();
    cnt[tid] = v;
    __syncthreads();
    for (int o = 1; o < 512; o <<= 1) {
        int t = (tid >= o) ? cnt[tid - o] : 0;
        __syncthreads();
        cnt[tid] += t;
        __syncthreads();
    }
    int excl = cnt[tid] - v;
    int node = b * BSZ + tid;
    if (node < NN) rp[node] = e0 + excl;
    fill[tid] = e0 + excl;
    __syncthreads();
    for (int k = tid; k < m; k += 512) {
        uint32_t e = ebuf[e0 + k];
        int pos = atomicAdd(&fill[e >> 17], 1);
        colx[pos] = (int)(e & 0x1FFFF);
    }
}

// ---------- W2/W3 -> MFMA-fragment-order split-f16 (hi + residual lo), 32 blocks ----------
__global__ void k_wt(const float* __restrict__ W2, const float* __restrict__ W3,
                     f16* __restrict__ wout) {
    int layer = blockIdx.x >> 4, lb = blockIdx.x & 15;
    const float* W = layer ? W3 : W2;
    f16* hi = wout + (size_t)layer * 2 * 2048 * 8;
    f16* lo = hi + 2048 * 8;
    for (int s = lb * 128 + threadIdx.x; s < (lb + 1) * 128; s += 256) {
        int kk = s >> 9, nt = (s >> 6) & 7, l = s & 63;
        int n = nt * 16 + (l & 15), k0 = kk * 32 + (l >> 4) * 8;
        f16x8 vh, vl;
#pragma unroll
        for (int j = 0; j < 8; j++) {
            float v = W[(long)(k0 + j) * HC + n];
            f16 h = (f16)v;
            vh[j] = h;
            vl[j] = (f16)(v - (float)h);
        }
        *(f16x8*)(hi + (size_t)s * 8) = vh;
        *(f16x8*)(lo + (size_t)s * 8) = vl;
    }
}

// ---------- layer-1 logits + x16 convert + pv compute (fused) ----------
__global__ __launch_bounds__(256) void k_att1(const float* __restrict__ x,
                                              const float* __restrict__ W1,
                                              const float* __restrict__ a1s,
                                              const float* __restrict__ a1d,
                                              f16* __restrict__ x16,
                                              float* __restrict__ als, float* __restrict__ ald) {
    __shared__ float sIn[128 * 33];
    __shared__ float spv[128];
    int t = threadIdx.x;
    long n0 = (long)blockIdx.x * 128;
    if (t < 128) {
        int sd = t >> 6, h = (t >> 5) & 1, f = t & 31;
        const float* a = sd ? a1d : a1s;
        float acc = 0.f;
        for (int c = 0; c < 64; c++) acc = fmaf(W1[f * HC + h * 64 + c], a[h * 64 + c], acc);
        spv[t] = acc;
    }
    for (int c = t; c < 128 * 8; c += 256) {
        int row = c >> 3, col = (c & 7) * 4;
        long gn = n0 + row;
        if (gn < NN) {
            float4 v = *(const float4*)(x + gn * 32 + col);
            float* dst = &sIn[row * 33 + col];
            dst[0] = v.x; dst[1] = v.y; dst[2] = v.z; dst[3] = v.w;
            f16x4 o;
            o[0] = (f16)v.x; o[1] = (f16)v.y; o[2] = (f16)v.z; o[3] = (f16)v.w;
            *(f16x4*)(x16 + gn * 32 + col) = o;
        }
    }
    __syncthreads();
    int n = t >> 1, h = t & 1;
    long gn = n0 + n;
    if (gn >= NN) return;
    const float* row = &sIn[n * 33];
    const float* as_ = &spv[h * 32];
    const float* ad_ = &spv[64 + h * 32];
    float s_ = 0.f, d_ = 0.f;
#pragma unroll
    for (int f = 0; f < 32; f++) {
        float v = row[f];
        s_ = fmaf(v, as_[f], s_);
        d_ = fmaf(v, ad_[f], d_);
    }
    als[2 * gn + h] = s_;
    ald[2 * gn + h] = d_;
}

// ---------- layer-1 aggregation: 4 edge-groups x 16 lanes, f16x2/lane -> xbar f16 ----------
__global__ __launch_bounds__(256) void k_aggx(const int* __restrict__ rp, const int* __restrict__ colx,
                                              const f16* __restrict__ x16,
                                              const float* __restrict__ als, const float* __restrict__ ald,
                                              f16* __restrict__ xbar) {
    int wid = blockIdx.x * 4 + (threadIdx.x >> 6);
    int lane = threadIdx.x & 63;
    int g = lane >> 4, li = lane & 15;
    int start = rp[wid], end = rp[wid + 1];
    float2 adv = *(const float2*)(ald + 2 * wid);
    float a00 = 0.f, a01 = 0.f, a10 = 0.f, a11 = 0.f, ws0 = 0.f, ws1 = 0.f;
#pragma unroll 8
    for (int j0 = start; j0 < end; j0 += 4) {
        int j = j0 + g;
        int jc = j < end ? j : end - 1;
        int s = colx[jc];
        float2 asv = *(const float2*)(als + 2 * s);
        float e0 = asv.x + adv.x, e1 = asv.y + adv.y;
        e0 = fmaxf(e0, 0.2f * e0);
        e1 = fmaxf(e1, 0.2f * e1);
        float w0 = __expf(e0), w1 = __expf(e1);
        if (j >= end) { w0 = 0.f; w1 = 0.f; }
        ws0 += w0; ws1 += w1;
        f16x2 xv = *(const f16x2*)(x16 + (long)s * 32 + li * 2);
        float f0 = (float)xv[0], f1 = (float)xv[1];
        a00 = fmaf(w0, f0, a00); a01 = fmaf(w0, f1, a01);
        a10 = fmaf(w1, f0, a10); a11 = fmaf(w1, f1, a11);
    }
#pragma unroll
    for (int o = 16; o <= 32; o <<= 1) {
        ws0 += __shfl_xor(ws0, o); ws1 += __shfl_xor(ws1, o);
        a00 += __shfl_xor(a00, o); a01 += __shfl_xor(a01, o);
        a10 += __shfl_xor(a10, o); a11 += __shfl_xor(a11, o);
    }
    if (g == 0) {
        float inv = 1.0f / ws0;
        f16x2 o; o[0] = (f16)(a00 * inv); o[1] = (f16)(a01 * inv);
        *(f16x2*)(xbar + (long)wid * 64 + li * 2) = o;
    } else if (g == 1) {
        float inv = 1.0f / ws1;
        f16x2 o; o[0] = (f16)(a10 * inv); o[1] = (f16)(a11 * inv);
        *(f16x2*)(xbar + (long)wid * 64 + 32 + li * 2) = o;
    }
}

// ---------- layer-1 post GEMM (block-diag K=32/head) + bias + prelu -> f16 ----------
__global__ __launch_bounds__(256) void k_post1(const f16* __restrict__ xb,
                                               const float* __restrict__ W1,
                                               const float* __restrict__ b1,
                                               const float* __restrict__ pap,
                                               f16* __restrict__ outp) {
    __shared__ __align__(16) float sIn[64 * 64];
    __shared__ __align__(16) float sW[32 * HC];
    __shared__ float sB[HC];
    int tid = threadIdx.x;
    long n0 = (long)blockIdx.x * 64;
    for (int c = tid; c < 64 * 8; c += 256) {
        int row = c >> 3, col = (c & 7) * 8;
        long gn = n0 + row;
        f16x8 v = {};
        if (gn < NN) v = *(const f16x8*)(xb + gn * 64 + col);
#pragma unroll
        for (int j = 0; j < 8; j++) sIn[row * 64 + col + j] = (float)v[j];
    }
    for (int c = tid; c < 32 * HC / 4; c += 256) ((float4*)sW)[c] = ((const float4*)W1)[c];
    if (tid < HC) sB[tid] = b1[tid];
    __syncthreads();
    int cg = tid & 31, ng = tid >> 5, head = cg >> 4;
    float4 acc[8];
#pragma unroll
    for (int i = 0; i < 8; i++) acc[i] = make_float4(0.f, 0.f, 0.f, 0.f);
    for (int k = 0; k < 32; k++) {
        float4 w = *(const float4*)(sW + k * HC + cg * 4);
#pragma unroll
        for (int i = 0; i < 8; i++) {
            float a = sIn[(ng * 8 + i) * 64 + head * 32 + k];
            acc[i].x = fmaf(a, w.x, acc[i].x);
            acc[i].y = fmaf(a, w.y, acc[i].y);
            acc[i].z = fmaf(a, w.z, acc[i].z);
            acc[i].w = fmaf(a, w.w, acc[i].w);
        }
    }
    float pa = pap[0];
    float4 b = *(const float4*)(sB + cg * 4);
#pragma unroll
    for (int i = 0; i < 8; i++) {
        long n = n0 + ng * 8 + i;
        if (n < NN) {
            float o0 = acc[i].x + b.x, o1 = acc[i].y + b.y;
            float o2 = acc[i].z + b.z, o3 = acc[i].w + b.w;
            o0 = o0 >= 0.f ? o0 : pa * o0;
            o1 = o1 >= 0.f ? o1 : pa * o1;
            o2 = o2 >= 0.f ? o2 : pa * o2;
            o3 = o3 >= 0.f ? o3 : pa * o3;
            f16x4 o; o[0] = (f16)o0; o[1] = (f16)o1; o[2] = (f16)o2; o[3] = (f16)o3;
            *(f16x4*)(outp + n * HC + cg * 4) = o;
        }
    }
}

// ---------- MFMA GEMM: h16 = in16 @ (Whi+Wlo), B staged in LDS; fused att projections ----------
__global__ __launch_bounds__(256) void k_gemmM(const f16* __restrict__ in16,
                                               const f16* __restrict__ wfrag,
                                               const float* __restrict__ avs,
                                               const float* __restrict__ avd,
                                               f16* __restrict__ h16,
                                               float* __restrict__ als, float* __restrict__ ald) {
    extern __shared__ f16 sB[];  // 32768 f16 = 64KB: [0..16383]=hi, [16384..]=lo
    int tid = threadIdx.x;
    for (int i = tid; i < 4096; i += 256) ((uint4*)sB)[i] = ((const uint4*)wfrag)[i];
    __syncthreads();
    int w = tid >> 6, l = tid & 63, q = l >> 4, m = l & 15;
    long n0 = (long)blockIdx.x * 64;
    long rowg = n0 + w * 16 + m;
    bool rok = rowg < NN;
    f32x4 acc[8];
#pragma unroll
    for (int i = 0; i < 8; i++) acc[i] = (f32x4){0.f, 0.f, 0.f, 0.f};
#pragma unroll
    for (int kk = 0; kk < 4; kk++) {
        f16x8 a = {};
        if (rok) a = *(const f16x8*)(in16 + rowg * HC + kk * 32 + q * 8);
#pragma unroll
        for (int nt = 0; nt < 8; nt++) {
            f16x8 bh = *(const f16x8*)(sB + ((kk * 8 + nt) * 64 + l) * 8);
            f16x8 bl = *(const f16x8*)(sB + 16384 + ((kk * 8 + nt) * 64 + l) * 8);
            acc[nt] = __builtin_amdgcn_mfma_f32_16x16x32_f16(a, bh, acc[nt], 0, 0, 0);
            acc[nt] = __builtin_amdgcn_mfma_f32_16x16x32_f16(a, bl, acc[nt], 0, 0, 0);
        }
    }
    float as_[8], ad_[8];
#pragma unroll
    for (int nt = 0; nt < 8; nt++) { as_[nt] = avs[nt * 16 + m]; ad_[nt] = avd[nt * 16 + m]; }
#pragma unroll
    for (int r = 0; r < 4; r++) {
        long rg = n0 + w * 16 + q * 4 + r;   // C/D: row = q*4 + r, col = nt*16 + m
        bool ok = rg < NN;
        float s0 = 0.f, s1 = 0.f, d0 = 0.f, d1 = 0.f;
#pragma unroll
        for (int nt = 0; nt < 4; nt++) {
            float v = acc[nt][r];
            s0 = fmaf(v, as_[nt], s0); d0 = fmaf(v, ad_[nt], d0);
        }
#pragma unroll
        for (int nt = 4; nt < 8; nt++) {
            float v = acc[nt][r];
            s1 = fmaf(v, as_[nt], s1); d1 = fmaf(v, ad_[nt], d1);
        }
        if (ok) {
#pragma unroll
            for (int nt = 0; nt < 8; nt++) h16[rg * HC + nt * 16 + m] = (f16)acc[nt][r];
        }
#pragma unroll
        for (int o = 1; o <= 8; o <<= 1) {
            s0 += __shfl_xor(s0, o); s1 += __shfl_xor(s1, o);
            d0 += __shfl_xor(d0, o); d1 += __shfl_xor(d1, o);
        }
        if (ok && m == 0) {
            als[2 * rg] = s0; als[2 * rg + 1] = s1;
            ald[2 * rg] = d0; ald[2 * rg + 1] = d1;
        }
    }
}

// ---------- aggregation over h16: 4 edges/iter, 16 lanes/edge, f16 output ----------
template <int MEAN>
__global__ __launch_bounds__(256) void k_agg(const int* __restrict__ rp, const int* __restrict__ colx,
                                             const f16* __restrict__ h,
                                             const float* __restrict__ als, const float* __restrict__ ald,
                                             const float* __restrict__ bias,
                                             const float* __restrict__ pap,
                                             f16* __restrict__ out16) {
    int wid = blockIdx.x * 4 + (threadIdx.x >> 6);
    int lane = threadIdx.x & 63;
    int g = lane >> 4, li = lane & 15;
    int start = rp[wid], end = rp[wid + 1];
    float2 adv = *(const float2*)(ald + 2 * wid);
    float acc[8];
#pragma unroll
    for (int k = 0; k < 8; k++) acc[k] = 0.f;
    float ws0 = 0.f, ws1 = 0.f;
    bool head1 = li >= 8;
#pragma unroll 8
    for (int j0 = start; j0 < end; j0 += 4) {
        int j = j0 + g;
        int jc = j < end ? j : end - 1;
        int s = colx[jc];
        float2 asv = *(const float2*)(als + 2 * s);
        float e0 = asv.x + adv.x, e1 = asv.y + adv.y;
        e0 = fmaxf(e0, 0.2f * e0);
        e1 = fmaxf(e1, 0.2f * e1);
        float w0 = __expf(e0), w1 = __expf(e1);
        if (j >= end) { w0 = 0.f; w1 = 0.f; }
        ws0 += w0; ws1 += w1;
        f16x8 hv = *(const f16x8*)(h + (long)s * HC + li * 8);
        float wsel = head1 ? w1 : w0;
#pragma unroll
        for (int k = 0; k < 8; k++) acc[k] = fmaf(wsel, (float)hv[k], acc[k]);
    }
#pragma unroll
    for (int o = 16; o <= 32; o <<= 1) {
        ws0 += __shfl_xor(ws0, o);
        ws1 += __shfl_xor(ws1, o);
#pragma unroll
        for (int k = 0; k < 8; k++) acc[k] += __shfl_xor(acc[k], o);
    }
    float pa = pap[0];
    if (!MEAN) {
        float inv = 1.0f / (head1 ? ws1 : ws0);
        int c = li * 8 + g * 2;
        float2 bu = *(const float2*)(bias + c);
        float o0 = acc[g * 2] * inv + bu.x;
        float o1 = acc[g * 2 + 1] * inv + bu.y;
        o0 = o0 >= 0.f ? o0 : pa * o0;
        o1 = o1 >= 0.f ? o1 : pa * o1;
        f16x2 o; o[0] = (f16)o0; o[1] = (f16)o1;
        *(f16x2*)(out16 + (long)wid * HC + c) = o;
    } else {
        float inv = 1.0f / (head1 ? ws1 : ws0);
        float v0 = acc[g * 2] * inv, v1 = acc[g * 2 + 1] * inv;
        float p0 = __shfl_xor(v0, 8), p1 = __shfl_xor(v1, 8);
        if (!head1) {
            int c = li * 8 + g * 2;
            float2 bu = *(const float2*)(bias + c);
            float o0 = 0.5f * (v0 + p0) + bu.x;
            float o1 = 0.5f * (v1 + p1) + bu.y;
            o0 = o0 >= 0.f ? o0 : pa * o0;
            o1 = o1 >= 0.f ? o1 : pa * o1;
            f16x2 o; o[0] = (f16)o0; o[1] = (f16)o1;
            *(f16x2*)(out16 + (long)wid * HID + c) = o;
        }
    }
}

// ---------- classifier (f16 input) ----------
__global__ __launch_bounds__(256) void k_cls(const f16* __restrict__ hin,
                                             const float* __restrict__ Wc,
                                             const float* __restrict__ bcp,
                                             float* __restrict__ outp) {
    __shared__ float sW[HID * NCLS];
    __shared__ float sb[NCLS];
    int tid = threadIdx.x;
    for (int c = tid; c < HID * NCLS; c += 256) sW[c] = Wc[c];
    if (tid < NCLS) sb[tid] = bcp[tid];
    __syncthreads();
    int n = blockIdx.x * 256 + tid;
    if (n >= NN) return;
    float o[NCLS];
#pragma unroll
    for (int k = 0; k < NCLS; k++) o[k] = sb[k];
    const f16x8* row = (const f16x8*)(hin + (long)n * HID);
#pragma unroll
    for (int cc = 0; cc < 8; cc++) {
        f16x8 rv = row[cc];
#pragma unroll
        for (int j = 0; j < 8; j++) {
            float v = (float)rv[j];
            int c = cc * 8 + j;
#pragma unroll
            for (int k = 0; k < NCLS; k++) o[k] = fmaf(v, sW[c * NCLS + k], o[k]);
        }
    }
#pragma unroll
    for (int k = 0; k < NCLS; k += 2)
        *(float2*)(outp + (long)n * NCLS + k) = make_float2(o[k], o[k + 1]);
}

extern "C" void kernel_launch(void* const* d_in, const int* in_sizes, int n_in,
                              void* d_out, int out_size, void* d_ws, size_t ws_size,
                              hipStream_t stream) {
    const float* x   = (const float*)d_in[0];
    const int*   ei  = (const int*)d_in[1];
    const float* W1  = (const float*)d_in[2];
    const float* a1s = (const float*)d_in[3];
    const float* a1d = (const float*)d_in[4];
    const float* b1  = (const float*)d_in[5];
    const float* W2  = (const float*)d_in[6];
    const float* a2s = (const float*)d_in[7];
    const float* a2d = (const float*)d_in[8];
    const float* b2  = (const float*)d_in[9];
    const float* W3  = (const float*)d_in[10];
    const float* a3s = (const float*)d_in[11];
    const float* a3d = (const float*)d_in[12];
    const float* b3  = (const float*)d_in[13];
    const float* pa  = (const float*)d_in[14];
    const float* Wc  = (const float*)d_in[15];
    const float* bc  = (const float*)d_in[16];
    float* out = (float*)d_out;

    char* w = (char*)d_ws;
    size_t off = 0;
    auto take = [&](size_t b) { void* p = w + off; off += (b + 255) & ~(size_t)255; return p; };
    int* rp      = (int*)take((size_t)(NN + 1) * 4);
    int* colx    = (int*)take((size_t)ET * 4);
    int* hgrid   = (int*)take((size_t)NPB * NBK * 4);
    int* bstart  = (int*)take((size_t)(NBK + 1) * 4);
    float* als   = (float*)take((size_t)NN * 8);
    float* ald   = (float*)take((size_t)NN * 8);
    f16* wfrag   = (f16*)take((size_t)2 * 2 * 2048 * 8 * 2);  // [layer][hi/lo][2048][8]
    f16* x16     = (f16*)take((size_t)NN * 32 * 2);
    f16* h16     = (f16*)take((size_t)NN * HC * 2);
    f16* g16     = (f16*)take((size_t)NN * HC * 2);
    f16* xbar    = (f16*)take((size_t)NN * 64 * 2);
    f16* mean16  = (f16*)take((size_t)NN * HID * 2);
    uint32_t* ebuf = (uint32_t*)h16;  // alias: ebuf dead before h16's first write

    int nb = (NN + 255) / 256;
    int gb = (NN + 63) / 64;
    int ab = NN / 4;
    int tb = (NN + 127) / 128;

    // CSR build (4 kernels, no global atomics)
    k_hist<<<NPB, 256, 0, stream>>>(ei, hgrid);
    k_bscan<<<1, 256, 0, stream>>>(hgrid, bstart, rp);
    k_part<<<NPB, 256, 0, stream>>>(ei, hgrid, ebuf);
    k_build<<<NBK, 512, 0, stream>>>(ebuf, bstart, rp, colx);
    // W fragment tables
    k_wt<<<32, 256, 0, stream>>>(W2, W3, wfrag);

    // layer 1 (commuted)
    k_att1<<<tb, 256, 0, stream>>>(x, W1, a1s, a1d, x16, als, ald);
    k_aggx<<<ab, 256, 0, stream>>>(rp, colx, x16, als, ald, xbar);
    k_post1<<<gb, 256, 0, stream>>>(xbar, W1, b1, pa, g16);
    // layer 2
    k_gemmM<<<gb, 256, 65536, stream>>>(g16, wfrag, a2s, a2d, h16, als, ald);
    k_agg<0><<<ab, 256, 0, stream>>>(rp, colx, h16, als, ald, b2, pa, g16);
    // layer 3 (head mean)
    k_gemmM<<<gb, 256, 65536, stream>>>(g16, wfrag + (size_t)2 * 2048 * 8, a3s, a3d, h16, als, ald);
    k_agg<1><<<ab, 256, 0, stream>>>(rp, colx, h16, als, ald, b3, pa, mean16);
    // classifier
    k_cls<<<nb, 256, 0, stream>>>(mean16, Wc, bc, out);
}

// Round 9
// 430.252 us; speedup vs baseline: 1.3826x; 1.3826x over previous
//
#include <hip/hip_runtime.h>
#include <stdint.h>

#define NN 100000
#define NE 1600000
#define ET (NE + NN)
#define HC 128
#define HID 64
#define NCLS 12
#define BSZ 512
#define NBK ((NN + BSZ - 1) / BSZ)      // 196
#define CHUNK 8192
#define NPB ((ET + CHUNK - 1) / CHUNK)  // 208

typedef _Float16 f16;
typedef _Float16 f16x2 __attribute__((ext_vector_type(2)));
typedef _Float16 f16x4 __attribute__((ext_vector_type(4)));
typedef _Float16 f16x8 __attribute__((ext_vector_type(8)));
typedef float f32x4 __attribute__((ext_vector_type(4)));

// ---------- CSR build: bucketed counting sort, no global atomics ----------
__global__ __launch_bounds__(256) void k_hist(const int* __restrict__ ei, int* __restrict__ hgrid) {
    __shared__ int h[NBK];
    int tid = threadIdx.x;
    for (int b = tid; b < NBK; b += 256) h[b] = 0;
    __syncthreads();
    long base = (long)blockIdx.x * CHUNK;
#pragma unroll
    for (int k = 0; k < CHUNK / 256; k++) {
        long i = base + k * 256 + tid;
        if (i < ET) {
            int d = (i < NE) ? ei[NE + i] : (int)(i - NE);
            atomicAdd(&h[d >> 9], 1);
        }
    }
    __syncthreads();
    for (int b = tid; b < NBK; b += 256) hgrid[blockIdx.x * NBK + b] = h[b];
}

__global__ __launch_bounds__(256) void k_bscan(int* __restrict__ hgrid,
                                               int* __restrict__ bucketStart,
                                               int* __restrict__ rp) {
    __shared__ int s[256];
    int tid = threadIdx.x;
    int tot = 0;
    if (tid < NBK)
        for (int b = 0; b < NPB; b++) tot += hgrid[b * NBK + tid];
    s[tid] = tot;
    __syncthreads();
    for (int o = 1; o < 256; o <<= 1) {
        int t = (tid >= o) ? s[tid - o] : 0;
        __syncthreads();
        s[tid] += t;
        __syncthreads();
    }
    int excl = s[tid] - tot;
    if (tid < NBK) {
        bucketStart[tid] = excl;
        int run = excl;
        for (int b = 0; b < NPB; b++) {
            int t = hgrid[b * NBK + tid];
            hgrid[b * NBK + tid] = run;
            run += t;
        }
    }
    if (tid == 0) { bucketStart[NBK] = ET; rp[NN] = ET; }
}

__global__ __launch_bounds__(256) void k_part(const int* __restrict__ ei,
                                              const int* __restrict__ hgrid,
                                              uint32_t* __restrict__ ebuf) {
    __shared__ int h[NBK];
    __shared__ int base[NBK];
    int tid = threadIdx.x;
    for (int b = tid; b < NBK; b += 256) {
        base[b] = hgrid[blockIdx.x * NBK + b];
        h[b] = 0;
    }
    __syncthreads();
    long cbase = (long)blockIdx.x * CHUNK;
#pragma unroll
    for (int k = 0; k < CHUNK / 256; k++) {
        long i = cbase + k * 256 + tid;
        if (i < ET) {
            int s, d;
            if (i < NE) { s = ei[i]; d = ei[NE + i]; } else { s = d = (int)(i - NE); }
            int bk = d >> 9;
            int off = atomicAdd(&h[bk], 1);
            ebuf[base[bk] + off] = (uint32_t)s | ((uint32_t)(d & 511) << 17);
        }
    }
}

__global__ __launch_bounds__(512) void k_build(const uint32_t* __restrict__ ebuf,
                                               const int* __restrict__ bucketStart,
                                               int* __restrict__ rp, int* __restrict__ colx) {
    __shared__ int cnt[BSZ];
    __shared__ int fill[BSZ];
    int b = blockIdx.x, tid = threadIdx.x;
    int e0 = bucketStart[b], e1 = bucketStart[b + 1], m = e1 - e0;
    cnt[tid] = 0;
    __syncthreads();
    for (int k = tid; k < m; k += 512) atomicAdd(&cnt[ebuf[e0 + k] >> 17], 1);
    __syncthreads();
    int v = cnt[tid];
    __syncthreads();
    cnt[tid] = v;
    __syncthreads();
    for (int o = 1; o < 512; o <<= 1) {
        int t = (tid >= o) ? cnt[tid - o] : 0;
        __syncthreads();
        cnt[tid] += t;
        __syncthreads();
    }
    int excl = cnt[tid] - v;
    int node = b * BSZ + tid;
    if (node < NN) rp[node] = e0 + excl;
    fill[tid] = e0 + excl;
    __syncthreads();
    for (int k = tid; k < m; k += 512) {
        uint32_t e = ebuf[e0 + k];
        int pos = atomicAdd(&fill[e >> 17], 1);
        colx[pos] = (int)(e & 0x1FFFF);
    }
}

// ---------- W2/W3 -> MFMA-fragment-order split-f16 (hi + residual lo), 32 blocks ----------
__global__ void k_wt(const float* __restrict__ W2, const float* __restrict__ W3,
                     f16* __restrict__ wout) {
    int layer = blockIdx.x >> 4, lb = blockIdx.x & 15;
    const float* W = layer ? W3 : W2;
    f16* hi = wout + (size_t)layer * 2 * 2048 * 8;
    f16* lo = hi + 2048 * 8;
    for (int s = lb * 128 + threadIdx.x; s < (lb + 1) * 128; s += 256) {
        int kk = s >> 9, nt = (s >> 6) & 7, l = s & 63;
        int n = nt * 16 + (l & 15), k0 = kk * 32 + (l >> 4) * 8;
        f16x8 vh, vl;
#pragma unroll
        for (int j = 0; j < 8; j++) {
            float v = W[(long)(k0 + j) * HC + n];
            f16 h = (f16)v;
            vh[j] = h;
            vl[j] = (f16)(v - (float)h);
        }
        *(f16x8*)(hi + (size_t)s * 8) = vh;
        *(f16x8*)(lo + (size_t)s * 8) = vl;
    }
}

// ---------- layer-1 logits + x16 convert + pv compute (fused) ----------
__global__ __launch_bounds__(256) void k_att1(const float* __restrict__ x,
                                              const float* __restrict__ W1,
                                              const float* __restrict__ a1s,
                                              const float* __restrict__ a1d,
                                              f16* __restrict__ x16,
                                              float* __restrict__ als, float* __restrict__ ald) {
    __shared__ float sIn[128 * 33];
    __shared__ float spv[128];
    int t = threadIdx.x;
    long n0 = (long)blockIdx.x * 128;
    if (t < 128) {
        int sd = t >> 6, h = (t >> 5) & 1, f = t & 31;
        const float* a = sd ? a1d : a1s;
        float acc = 0.f;
        for (int c = 0; c < 64; c++) acc = fmaf(W1[f * HC + h * 64 + c], a[h * 64 + c], acc);
        spv[t] = acc;
    }
    for (int c = t; c < 128 * 8; c += 256) {
        int row = c >> 3, col = (c & 7) * 4;
        long gn = n0 + row;
        if (gn < NN) {
            float4 v = *(const float4*)(x + gn * 32 + col);
            float* dst = &sIn[row * 33 + col];
            dst[0] = v.x; dst[1] = v.y; dst[2] = v.z; dst[3] = v.w;
            f16x4 o;
            o[0] = (f16)v.x; o[1] = (f16)v.y; o[2] = (f16)v.z; o[3] = (f16)v.w;
            *(f16x4*)(x16 + gn * 32 + col) = o;
        }
    }
    __syncthreads();
    int n = t >> 1, h = t & 1;
    long gn = n0 + n;
    if (gn >= NN) return;
    const float* row = &sIn[n * 33];
    const float* as_ = &spv[h * 32];
    const float* ad_ = &spv[64 + h * 32];
    float s_ = 0.f, d_ = 0.f;
#pragma unroll
    for (int f = 0; f < 32; f++) {
        float v = row[f];
        s_ = fmaf(v, as_[f], s_);
        d_ = fmaf(v, ad_[f], d_);
    }
    als[2 * gn + h] = s_;
    ald[2 * gn + h] = d_;
}

// ---------- layer-1 aggregation: 4 edge-groups x 16 lanes, f16x2/lane -> xbar f16 ----------
__global__ __launch_bounds__(256) void k_aggx(const int* __restrict__ rp, const int* __restrict__ colx,
                                              const f16* __restrict__ x16,
                                              const float* __restrict__ als, const float* __restrict__ ald,
                                              f16* __restrict__ xbar) {
    int wid = blockIdx.x * 4 + (threadIdx.x >> 6);
    int lane = threadIdx.x & 63;
    int g = lane >> 4, li = lane & 15;
    int start = rp[wid], end = rp[wid + 1];
    float2 adv = *(const float2*)(ald + 2 * wid);
    float a00 = 0.f, a01 = 0.f, a10 = 0.f, a11 = 0.f, ws0 = 0.f, ws1 = 0.f;
#pragma unroll 4
    for (int j0 = start; j0 < end; j0 += 4) {
        int j = j0 + g;
        int jc = j < end ? j : end - 1;
        int s = colx[jc];
        float2 asv = *(const float2*)(als + 2 * s);
        float e0 = asv.x + adv.x, e1 = asv.y + adv.y;
        e0 = fmaxf(e0, 0.2f * e0);
        e1 = fmaxf(e1, 0.2f * e1);
        float w0 = __expf(e0), w1 = __expf(e1);
        if (j >= end) { w0 = 0.f; w1 = 0.f; }
        ws0 += w0; ws1 += w1;
        f16x2 xv = *(const f16x2*)(x16 + (long)s * 32 + li * 2);
        float f0 = (float)xv[0], f1 = (float)xv[1];
        a00 = fmaf(w0, f0, a00); a01 = fmaf(w0, f1, a01);
        a10 = fmaf(w1, f0, a10); a11 = fmaf(w1, f1, a11);
    }
#pragma unroll
    for (int o = 16; o <= 32; o <<= 1) {
        ws0 += __shfl_xor(ws0, o); ws1 += __shfl_xor(ws1, o);
        a00 += __shfl_xor(a00, o); a01 += __shfl_xor(a01, o);
        a10 += __shfl_xor(a10, o); a11 += __shfl_xor(a11, o);
    }
    if (g == 0) {
        float inv = 1.0f / ws0;
        f16x2 o; o[0] = (f16)(a00 * inv); o[1] = (f16)(a01 * inv);
        *(f16x2*)(xbar + (long)wid * 64 + li * 2) = o;
    } else if (g == 1) {
        float inv = 1.0f / ws1;
        f16x2 o; o[0] = (f16)(a10 * inv); o[1] = (f16)(a11 * inv);
        *(f16x2*)(xbar + (long)wid * 64 + 32 + li * 2) = o;
    }
}

// ---------- layer-1 post GEMM (block-diag K=32/head) + bias + prelu -> f16 ----------
__global__ __launch_bounds__(256) void k_post1(const f16* __restrict__ xb,
                                               const float* __restrict__ W1,
                                               const float* __restrict__ b1,
                                               const float* __restrict__ pap,
                                               f16* __restrict__ outp) {
    __shared__ __align__(16) float sIn[64 * 64];
    __shared__ __align__(16) float sW[32 * HC];
    __shared__ float sB[HC];
    int tid = threadIdx.x;
    long n0 = (long)blockIdx.x * 64;
    for (int c = tid; c < 64 * 8; c += 256) {
        int row = c >> 3, col = (c & 7) * 8;
        long gn = n0 + row;
        f16x8 v = {};
        if (gn < NN) v = *(const f16x8*)(xb + gn * 64 + col);
#pragma unroll
        for (int j = 0; j < 8; j++) sIn[row * 64 + col + j] = (float)v[j];
    }
    for (int c = tid; c < 32 * HC / 4; c += 256) ((float4*)sW)[c] = ((const float4*)W1)[c];
    if (tid < HC) sB[tid] = b1[tid];
    __syncthreads();
    int cg = tid & 31, ng = tid >> 5, head = cg >> 4;
    float4 acc[8];
#pragma unroll
    for (int i = 0; i < 8; i++) acc[i] = make_float4(0.f, 0.f, 0.f, 0.f);
    for (int k = 0; k < 32; k++) {
        float4 w = *(const float4*)(sW + k * HC + cg * 4);
#pragma unroll
        for (int i = 0; i < 8; i++) {
            float a = sIn[(ng * 8 + i) * 64 + head * 32 + k];
            acc[i].x = fmaf(a, w.x, acc[i].x);
            acc[i].y = fmaf(a, w.y, acc[i].y);
            acc[i].z = fmaf(a, w.z, acc[i].z);
            acc[i].w = fmaf(a, w.w, acc[i].w);
        }
    }
    float pa = pap[0];
    float4 b = *(const float4*)(sB + cg * 4);
#pragma unroll
    for (int i = 0; i < 8; i++) {
        long n = n0 + ng * 8 + i;
        if (n < NN) {
            float o0 = acc[i].x + b.x, o1 = acc[i].y + b.y;
            float o2 = acc[i].z + b.z, o3 = acc[i].w + b.w;
            o0 = o0 >= 0.f ? o0 : pa * o0;
            o1 = o1 >= 0.f ? o1 : pa * o1;
            o2 = o2 >= 0.f ? o2 : pa * o2;
            o3 = o3 >= 0.f ? o3 : pa * o3;
            f16x4 o; o[0] = (f16)o0; o[1] = (f16)o1; o[2] = (f16)o2; o[3] = (f16)o3;
            *(f16x4*)(outp + n * HC + cg * 4) = o;
        }
    }
}

// ---------- MFMA GEMM: h16 = in16 @ (Whi+Wlo), B-frags from global (L2-hot); fused proj ----------
__global__ __launch_bounds__(256) void k_gemmM(const f16* __restrict__ in16,
                                               const f16* __restrict__ wfrag,
                                               const float* __restrict__ avs,
                                               const float* __restrict__ avd,
                                               f16* __restrict__ h16,
                                               float* __restrict__ als, float* __restrict__ ald) {
    const f16* whi = wfrag;
    const f16* wlo = wfrag + 2048 * 8;
    int tid = threadIdx.x;
    int w = tid >> 6, l = tid & 63, q = l >> 4, m = l & 15;
    long n0 = (long)blockIdx.x * 64;
    long rowg = n0 + w * 16 + m;
    bool rok = rowg < NN;
    f32x4 acc[8];
#pragma unroll
    for (int i = 0; i < 8; i++) acc[i] = (f32x4){0.f, 0.f, 0.f, 0.f};
#pragma unroll
    for (int kk = 0; kk < 4; kk++) {
        f16x8 a = {};
        if (rok) a = *(const f16x8*)(in16 + rowg * HC + kk * 32 + q * 8);
#pragma unroll
        for (int nt = 0; nt < 8; nt++) {
            f16x8 bh = *(const f16x8*)(whi + ((kk * 8 + nt) * 64 + l) * 8);
            f16x8 bl = *(const f16x8*)(wlo + ((kk * 8 + nt) * 64 + l) * 8);
            acc[nt] = __builtin_amdgcn_mfma_f32_16x16x32_f16(a, bh, acc[nt], 0, 0, 0);
            acc[nt] = __builtin_amdgcn_mfma_f32_16x16x32_f16(a, bl, acc[nt], 0, 0, 0);
        }
    }
    float as_[8], ad_[8];
#pragma unroll
    for (int nt = 0; nt < 8; nt++) { as_[nt] = avs[nt * 16 + m]; ad_[nt] = avd[nt * 16 + m]; }
#pragma unroll
    for (int r = 0; r < 4; r++) {
        long rg = n0 + w * 16 + q * 4 + r;   // C/D: row = q*4 + r, col = nt*16 + m
        bool ok = rg < NN;
        float s0 = 0.f, s1 = 0.f, d0 = 0.f, d1 = 0.f;
#pragma unroll
        for (int nt = 0; nt < 4; nt++) {
            float v = acc[nt][r];
            s0 = fmaf(v, as_[nt], s0); d0 = fmaf(v, ad_[nt], d0);
        }
#pragma unroll
        for (int nt = 4; nt < 8; nt++) {
            float v = acc[nt][r];
            s1 = fmaf(v, as_[nt], s1); d1 = fmaf(v, ad_[nt], d1);
        }
        if (ok) {
#pragma unroll
            for (int nt = 0; nt < 8; nt++) h16[rg * HC + nt * 16 + m] = (f16)acc[nt][r];
        }
#pragma unroll
        for (int o = 1; o <= 8; o <<= 1) {
            s0 += __shfl_xor(s0, o); s1 += __shfl_xor(s1, o);
            d0 += __shfl_xor(d0, o); d1 += __shfl_xor(d1, o);
        }
        if (ok && m == 0) {
            als[2 * rg] = s0; als[2 * rg + 1] = s1;
            ald[2 * rg] = d0; ald[2 * rg + 1] = d1;
        }
    }
}

// ---------- aggregation over h16: 4 edges/iter, 16 lanes/edge, f16 output ----------
template <int MEAN>
__global__ __launch_bounds__(256) void k_agg(const int* __restrict__ rp, const int* __restrict__ colx,
                                             const f16* __restrict__ h,
                                             const float* __restrict__ als, const float* __restrict__ ald,
                                             const float* __restrict__ bias,
                                             const float* __restrict__ pap,
                                             f16* __restrict__ out16) {
    int wid = blockIdx.x * 4 + (threadIdx.x >> 6);
    int lane = threadIdx.x & 63;
    int g = lane >> 4, li = lane & 15;
    int start = rp[wid], end = rp[wid + 1];
    float2 adv = *(const float2*)(ald + 2 * wid);
    float acc[8];
#pragma unroll
    for (int k = 0; k < 8; k++) acc[k] = 0.f;
    float ws0 = 0.f, ws1 = 0.f;
    bool head1 = li >= 8;
#pragma unroll 4
    for (int j0 = start; j0 < end; j0 += 4) {
        int j = j0 + g;
        int jc = j < end ? j : end - 1;
        int s = colx[jc];
        float2 asv = *(const float2*)(als + 2 * s);
        float e0 = asv.x + adv.x, e1 = asv.y + adv.y;
        e0 = fmaxf(e0, 0.2f * e0);
        e1 = fmaxf(e1, 0.2f * e1);
        float w0 = __expf(e0), w1 = __expf(e1);
        if (j >= end) { w0 = 0.f; w1 = 0.f; }
        ws0 += w0; ws1 += w1;
        f16x8 hv = *(const f16x8*)(h + (long)s * HC + li * 8);
        float wsel = head1 ? w1 : w0;
#pragma unroll
        for (int k = 0; k < 8; k++) acc[k] = fmaf(wsel, (float)hv[k], acc[k]);
    }
#pragma unroll
    for (int o = 16; o <= 32; o <<= 1) {
        ws0 += __shfl_xor(ws0, o);
        ws1 += __shfl_xor(ws1, o);
#pragma unroll
        for (int k = 0; k < 8; k++) acc[k] += __shfl_xor(acc[k], o);
    }
    float pa = pap[0];
    if (!MEAN) {
        float inv = 1.0f / (head1 ? ws1 : ws0);
        int c = li * 8 + g * 2;
        float2 bu = *(const float2*)(bias + c);
        float o0 = acc[g * 2] * inv + bu.x;
        float o1 = acc[g * 2 + 1] * inv + bu.y;
        o0 = o0 >= 0.f ? o0 : pa * o0;
        o1 = o1 >= 0.f ? o1 : pa * o1;
        f16x2 o; o[0] = (f16)o0; o[1] = (f16)o1;
        *(f16x2*)(out16 + (long)wid * HC + c) = o;
    } else {
        float inv = 1.0f / (head1 ? ws1 : ws0);
        float v0 = acc[g * 2] * inv, v1 = acc[g * 2 + 1] * inv;
        float p0 = __shfl_xor(v0, 8), p1 = __shfl_xor(v1, 8);
        if (!head1) {
            int c = li * 8 + g * 2;
            float2 bu = *(const float2*)(bias + c);
            float o0 = 0.5f * (v0 + p0) + bu.x;
            float o1 = 0.5f * (v1 + p1) + bu.y;
            o0 = o0 >= 0.f ? o0 : pa * o0;
            o1 = o1 >= 0.f ? o1 : pa * o1;
            f16x2 o; o[0] = (f16)o0; o[1] = (f16)o1;
            *(f16x2*)(out16 + (long)wid * HID + c) = o;
        }
    }
}

// ---------- classifier (f16 input) ----------
__global__ __launch_bounds__(256) void k_cls(const f16* __restrict__ hin,
                                             const float* __restrict__ Wc,
                                             const float* __restrict__ bcp,
                                             float* __restrict__ outp) {
    __shared__ float sW[HID * NCLS];
    __shared__ float sb[NCLS];
    int tid = threadIdx.x;
    for (int c = tid; c < HID * NCLS; c += 256) sW[c] = Wc[c];
    if (tid < NCLS) sb[tid] = bcp[tid];
    __syncthreads();
    int n = blockIdx.x * 256 + tid;
    if (n >= NN) return;
    float o[NCLS];
#pragma unroll
    for (int k = 0; k < NCLS; k++) o[k] = sb[k];
    const f16x8* row = (const f16x8*)(hin + (long)n * HID);
#pragma unroll
    for (int cc = 0; cc < 8; cc++) {
        f16x8 rv = row[cc];
#pragma unroll
        for (int j = 0; j < 8; j++) {
            float v = (float)rv[j];
            int c = cc * 8 + j;
#pragma unroll
            for (int k = 0; k < NCLS; k++) o[k] = fmaf(v, sW[c * NCLS + k], o[k]);
        }
    }
#pragma unroll
    for (int k = 0; k < NCLS; k += 2)
        *(float2*)(outp + (long)n * NCLS + k) = make_float2(o[k], o[k + 1]);
}

extern "C" void kernel_launch(void* const* d_in, const int* in_sizes, int n_in,
                              void* d_out, int out_size, void* d_ws, size_t ws_size,
                              hipStream_t stream) {
    const float* x   = (const float*)d_in[0];
    const int*   ei  = (const int*)d_in[1];
    const float* W1  = (const float*)d_in[2];
    const float* a1s = (const float*)d_in[3];
    const float* a1d = (const float*)d_in[4];
    const float* b1  = (const float*)d_in[5];
    const float* W2  = (const float*)d_in[6];
    const float* a2s = (const float*)d_in[7];
    const float* a2d = (const float*)d_in[8];
    const float* b2  = (const float*)d_in[9];
    const float* W3  = (const float*)d_in[10];
    const float* a3s = (const float*)d_in[11];
    const float* a3d = (const float*)d_in[12];
    const float* b3  = (const float*)d_in[13];
    const float* pa  = (const float*)d_in[14];
    const float* Wc  = (const float*)d_in[15];
    const float* bc  = (const float*)d_in[16];
    float* out = (float*)d_out;

    char* w = (char*)d_ws;
    size_t off = 0;
    auto take = [&](size_t b) { void* p = w + off; off += (b + 255) & ~(size_t)255; return p; };
    int* rp      = (int*)take((size_t)(NN + 1) * 4);
    int* colx    = (int*)take((size_t)ET * 4);
    int* hgrid   = (int*)take((size_t)NPB * NBK * 4);
    int* bstart  = (int*)take((size_t)(NBK + 1) * 4);
    float* als   = (float*)take((size_t)NN * 8);
    float* ald   = (float*)take((size_t)NN * 8);
    f16* wfrag   = (f16*)take((size_t)2 * 2 * 2048 * 8 * 2);  // [layer][hi/lo][2048][8]
    f16* x16     = (f16*)take((size_t)NN * 32 * 2);
    f16* h16     = (f16*)take((size_t)NN * HC * 2);
    f16* g16     = (f16*)take((size_t)NN * HC * 2);
    f16* xbar    = (f16*)take((size_t)NN * 64 * 2);
    f16* mean16  = (f16*)take((size_t)NN * HID * 2);
    uint32_t* ebuf = (uint32_t*)h16;  // alias: ebuf dead before h16's first write

    int nb = (NN + 255) / 256;
    int gb = (NN + 63) / 64;
    int ab = NN / 4;
    int tb = (NN + 127) / 128;

    // CSR build (4 kernels, no global atomics)
    k_hist<<<NPB, 256, 0, stream>>>(ei, hgrid);
    k_bscan<<<1, 256, 0, stream>>>(hgrid, bstart, rp);
    k_part<<<NPB, 256, 0, stream>>>(ei, hgrid, ebuf);
    k_build<<<NBK, 512, 0, stream>>>(ebuf, bstart, rp, colx);
    // W fragment tables
    k_wt<<<32, 256, 0, stream>>>(W2, W3, wfrag);

    // layer 1 (commuted)
    k_att1<<<tb, 256, 0, stream>>>(x, W1, a1s, a1d, x16, als, ald);
    k_aggx<<<ab, 256, 0, stream>>>(rp, colx, x16, als, ald, xbar);
    k_post1<<<gb, 256, 0, stream>>>(xbar, W1, b1, pa, g16);
    // layer 2
    k_gemmM<<<gb, 256, 0, stream>>>(g16, wfrag, a2s, a2d, h16, als, ald);
    k_agg<0><<<ab, 256, 0, stream>>>(rp, colx, h16, als, ald, b2, pa, g16);
    // layer 3 (head mean)
    k_gemmM<<<gb, 256, 0, stream>>>(g16, wfrag + (size_t)2 * 2048 * 8, a3s, a3d, h16, als, ald);
    k_agg<1><<<ab, 256, 0, stream>>>(rp, colx, h16, als, ald, b3, pa, mean16);
    // classifier
    k_cls<<<nb, 256, 0, stream>>>(mean16, Wc, bc, out);
}